// Round 1
// baseline (1520.794 us; speedup 1.0000x reference)
//
#include <hip/hip_runtime.h>
#include <math.h>

#define NEG_SLOPE 0.2f

__device__ __forceinline__ float lrelu(float x) { return x > 0.f ? x : NEG_SLOPE * x; }

// Sign-split float atomic max. Works with init bit pattern 0xFFFFFFFF:
//  - as int it is -1 (< any positive float's bits)
//  - as uint it is max (> any negative float's bits)
__device__ __forceinline__ void atomicMaxF(float* addr, float val) {
    if (val >= 0.0f) atomicMax((int*)addr, __float_as_int(val));
    else             atomicMin((unsigned int*)addr, __float_as_uint(val));
}

__device__ __forceinline__ void edge_sd(const int* __restrict__ ei, int edge, int E,
                                        int& src, int& dst) {
    if (edge < E) { src = ei[edge]; dst = ei[E + edge]; }
    else { src = edge - E; dst = src; }   // self-loop
}

// ---- Layer 1: node transform, in=5 -> out=64 (xl and xr) ----
__global__ void k_transform1(const float* __restrict__ x,
                             const float* __restrict__ W1l, const float* __restrict__ W1r,
                             float* __restrict__ xl, float* __restrict__ xr, int n) {
    __shared__ float sWl[5 * 64], sWr[5 * 64];
    int t = threadIdx.x;
    for (int i = t; i < 5 * 64; i += blockDim.x) { sWl[i] = W1l[i]; sWr[i] = W1r[i]; }
    __syncthreads();
    int tid = blockIdx.x * blockDim.x + t;
    if (tid >= n * 64) return;
    int node = tid >> 6, j = tid & 63;
    const float* xr_ = x + node * 5;
    float x0 = xr_[0], x1 = xr_[1], x2 = xr_[2], x3 = xr_[3], x4 = xr_[4];
    float al = x0 * sWl[j] + x1 * sWl[64 + j] + x2 * sWl[128 + j] + x3 * sWl[192 + j] + x4 * sWl[256 + j];
    float ar = x0 * sWr[j] + x1 * sWr[64 + j] + x2 * sWr[128 + j] + x3 * sWr[192 + j] + x4 * sWr[256 + j];
    xl[tid] = al; xr[tid] = ar;
}

// ---- Layer 1: per-(edge,head) attention logit + segment max ----
__global__ void k_edge1_e(const int* __restrict__ ei,
                          const float* __restrict__ xl, const float* __restrict__ xr,
                          const float* __restrict__ att1,
                          float* __restrict__ ebuf, float* __restrict__ m1,
                          int E, int ET) {
    int tid = blockIdx.x * blockDim.x + threadIdx.x;
    if (tid >= ET * 4) return;
    int edge = tid >> 2, h = tid & 3;
    int src, dst; edge_sd(ei, edge, E, src, dst);
    const float4* a4 = reinterpret_cast<const float4*>(xl + (size_t)src * 64 + h * 16);
    const float4* b4 = reinterpret_cast<const float4*>(xr + (size_t)dst * 64 + h * 16);
    const float4* t4 = reinterpret_cast<const float4*>(att1 + h * 16);
    float e = 0.f;
#pragma unroll
    for (int q = 0; q < 4; ++q) {
        float4 av = a4[q], bv = b4[q], tv = t4[q];
        e += lrelu(av.x + bv.x) * tv.x + lrelu(av.y + bv.y) * tv.y
           + lrelu(av.z + bv.z) * tv.z + lrelu(av.w + bv.w) * tv.w;
    }
    ebuf[tid] = e;
    atomicMaxF(&m1[dst * 4 + h], e);
}

// ---- Layer 1: p = exp(e - m[dst]), segment sum ----
__global__ void k_edge1_p(const int* __restrict__ ei,
                          float* __restrict__ ebuf,
                          const float* __restrict__ m1, float* __restrict__ denom1,
                          int E, int ET) {
    int tid = blockIdx.x * blockDim.x + threadIdx.x;
    if (tid >= ET * 4) return;
    int edge = tid >> 2, h = tid & 3;
    int src, dst; edge_sd(ei, edge, E, src, dst);
    float p = expf(ebuf[tid] - m1[dst * 4 + h]);
    ebuf[tid] = p;
    atomicAdd(&denom1[dst * 4 + h], p);
}

// ---- Layer 1: out[dst] += alpha * xl[src]  (one wave per edge, 64 feats) ----
__global__ void k_edge1_agg(const int* __restrict__ ei,
                            const float* __restrict__ xl,
                            const float* __restrict__ ebuf, const float* __restrict__ denom1,
                            float* __restrict__ out1, int E, int ET) {
    int tid = blockIdx.x * blockDim.x + threadIdx.x;
    int edge = tid >> 6;
    if (edge >= ET) return;
    int f = tid & 63, h = f >> 4;
    int src, dst; edge_sd(ei, edge, E, src, dst);
    float alpha = ebuf[(size_t)edge * 4 + h] / (denom1[dst * 4 + h] + 1e-16f);
    atomicAdd(&out1[(size_t)dst * 64 + f], alpha * xl[(size_t)src * 64 + f]);
}

// ---- Layer 2: h1 = relu(out1 + b1); hl2 = h1@W2l; hr2 = h1@W2r ----
__global__ void k_transform2(const float* __restrict__ out1, const float* __restrict__ b1,
                             const float* __restrict__ W2l, const float* __restrict__ W2r,
                             float* __restrict__ hl, float* __restrict__ hr, int n) {
    __shared__ float sh[4][64];
    int t = threadIdx.x;
    int local = t >> 6, j = t & 63;
    int node = blockIdx.x * 4 + local;
    if (node < n) {
        float v = out1[(size_t)node * 64 + j] + b1[j];
        sh[local][j] = v > 0.f ? v : 0.f;
    }
    __syncthreads();
    if (node >= n) return;
    float accl = 0.f, accr = 0.f;
#pragma unroll 8
    for (int k = 0; k < 64; ++k) {
        float hv = sh[local][k];
        accl += hv * W2l[k * 64 + j];
        accr += hv * W2r[k * 64 + j];
    }
    hl[(size_t)node * 64 + j] = accl;
    hr[(size_t)node * 64 + j] = accr;
}

// ---- Layer 2: per-edge logit (wave per edge, 64-lane dot) + segment max ----
__global__ void k_edge2_e(const int* __restrict__ ei,
                          const float* __restrict__ hl, const float* __restrict__ hr,
                          const float* __restrict__ att2,
                          float* __restrict__ ebuf, float* __restrict__ m2,
                          int E, int ET) {
    int tid = blockIdx.x * blockDim.x + threadIdx.x;
    int edge = tid >> 6;
    if (edge >= ET) return;
    int lane = threadIdx.x & 63;
    int src, dst; edge_sd(ei, edge, E, src, dst);
    float s = hl[(size_t)src * 64 + lane] + hr[(size_t)dst * 64 + lane];
    float v = lrelu(s) * att2[lane];
#pragma unroll
    for (int off = 32; off > 0; off >>= 1) v += __shfl_down(v, off, 64);
    if (lane == 0) {
        ebuf[edge] = v;
        atomicMaxF(&m2[dst], v);
    }
}

// ---- Layer 2: p = exp(e - m[dst]), segment sum ----
__global__ void k_edge2_p(const int* __restrict__ ei,
                          float* __restrict__ ebuf,
                          const float* __restrict__ m2, float* __restrict__ denom2,
                          int E, int ET) {
    int edge = blockIdx.x * blockDim.x + threadIdx.x;
    if (edge >= ET) return;
    int src, dst; edge_sd(ei, edge, E, src, dst);
    float p = expf(ebuf[edge] - m2[dst]);
    ebuf[edge] = p;
    atomicAdd(&denom2[dst], p);
}

// ---- Layer 2: out2[dst] += alpha * hl[src] (wave per edge) ----
__global__ void k_edge2_agg(const int* __restrict__ ei,
                            const float* __restrict__ hl,
                            const float* __restrict__ ebuf, const float* __restrict__ denom2,
                            float* __restrict__ out2, int E, int ET) {
    int tid = blockIdx.x * blockDim.x + threadIdx.x;
    int edge = tid >> 6;
    if (edge >= ET) return;
    int lane = threadIdx.x & 63;
    int src, dst; edge_sd(ei, edge, E, src, dst);
    float alpha = ebuf[edge] / (denom2[dst] + 1e-16f);
    atomicAdd(&out2[(size_t)dst * 64 + lane], alpha * hl[(size_t)src * 64 + lane]);
}

// ---- Pool: pooled[batch[node]] += relu(out2[node]+b2); cnt[g] += 1 ----
__global__ void k_pool(const float* __restrict__ out2, const float* __restrict__ b2,
                       const int* __restrict__ batch,
                       float* __restrict__ pooled, float* __restrict__ cnt, int n) {
    int tid = blockIdx.x * blockDim.x + threadIdx.x;
    if (tid >= n * 64) return;
    int node = tid >> 6, f = tid & 63;
    float v = out2[tid] + b2[f];
    v = v > 0.f ? v : 0.f;
    int g = batch[node];
    atomicAdd(&pooled[g * 64 + f], v);
    if (f == 0) atomicAdd(&cnt[g], 1.0f);
}

// ---- Predict: out[g] = dot(pooled[g]/max(cnt,1), Wp) + bp ----
__global__ void k_predict(const float* __restrict__ pooled, const float* __restrict__ cnt,
                          const float* __restrict__ Wp, const float* __restrict__ bp,
                          float* __restrict__ out, int G) {
    int tid = blockIdx.x * blockDim.x + threadIdx.x;
    int g = tid >> 6;
    if (g >= G) return;
    int lane = threadIdx.x & 63;
    float c = cnt[g];
    if (c < 1.f) c = 1.f;
    float v = (pooled[g * 64 + lane] / c) * Wp[lane];
#pragma unroll
    for (int off = 32; off > 0; off >>= 1) v += __shfl_down(v, off, 64);
    if (lane == 0) out[g] = v + bp[0];
}

extern "C" void kernel_launch(void* const* d_in, const int* in_sizes, int n_in,
                              void* d_out, int out_size, void* d_ws, size_t ws_size,
                              hipStream_t stream) {
    const float* x    = (const float*)d_in[0];
    const int*   ei   = (const int*)d_in[1];
    const int*   batch= (const int*)d_in[2];
    const float* W1l  = (const float*)d_in[3];
    const float* W1r  = (const float*)d_in[4];
    const float* att1 = (const float*)d_in[5];
    const float* b1   = (const float*)d_in[6];
    const float* W2l  = (const float*)d_in[7];
    const float* W2r  = (const float*)d_in[8];
    const float* att2 = (const float*)d_in[9];
    const float* b2   = (const float*)d_in[10];
    const float* Wp   = (const float*)d_in[11];
    const float* bp   = (const float*)d_in[12];
    float* out = (float*)d_out;

    const int n  = in_sizes[0] / 5;        // 50000
    const int E  = in_sizes[1] / 2;        // 1600000
    const int ET = E + n;                  // +self-loops
    const int G  = out_size;               // 512

    // ---- workspace layout (floats) ----
    float* ws = (float*)d_ws;
    size_t off = 0;
    float* buf_l  = ws + off; off += (size_t)n * 64;   // xl1 / hl2
    float* buf_r  = ws + off; off += (size_t)n * 64;   // xr1 / hr2
    float* e_buf  = ws + off; off += (size_t)ET * 4;   // e/p layer1; layer2 uses first ET
    float* m1     = ws + off; off += (size_t)n * 4;    // -inf init region start
    float* m2     = ws + off; off += (size_t)n;
    float* denom1 = ws + off; off += (size_t)n * 4;    // zero init region start
    float* denom2 = ws + off; off += (size_t)n;
    float* out1   = ws + off; off += (size_t)n * 64;
    float* out2   = ws + off; off += (size_t)n * 64;
    float* pooled = ws + off; off += (size_t)G * 64;
    float* cnt    = ws + off; off += (size_t)G;

    // init: m1..m2 -> 0xFF (acts as -inf for sign-split atomic max); denoms/outs/pool -> 0
    size_t ninf_bytes = ((size_t)n * 4 + n) * sizeof(float);
    size_t zero_bytes = ((size_t)n * 4 + n + (size_t)n * 64 * 2 + (size_t)G * 64 + G) * sizeof(float);
    hipMemsetAsync(m1, 0xFF, ninf_bytes, stream);
    hipMemsetAsync(denom1, 0, zero_bytes, stream);

    const int B = 256;
    // layer 1
    k_transform1<<<(n * 64 + B - 1) / B, B, 0, stream>>>(x, W1l, W1r, buf_l, buf_r, n);
    k_edge1_e<<<((size_t)ET * 4 + B - 1) / B, B, 0, stream>>>(ei, buf_l, buf_r, att1, e_buf, m1, E, ET);
    k_edge1_p<<<((size_t)ET * 4 + B - 1) / B, B, 0, stream>>>(ei, e_buf, m1, denom1, E, ET);
    k_edge1_agg<<<((size_t)ET * 64 + B - 1) / B, B, 0, stream>>>(ei, buf_l, e_buf, denom1, out1, E, ET);
    // layer 2
    k_transform2<<<(n + 3) / 4, B, 0, stream>>>(out1, b1, W2l, W2r, buf_l, buf_r, n);
    k_edge2_e<<<((size_t)ET * 64 + B - 1) / B, B, 0, stream>>>(ei, buf_l, buf_r, att2, e_buf, m2, E, ET);
    k_edge2_p<<<(ET + B - 1) / B, B, 0, stream>>>(ei, e_buf, m2, denom2, E, ET);
    k_edge2_agg<<<((size_t)ET * 64 + B - 1) / B, B, 0, stream>>>(ei, buf_l, e_buf, denom2, out2, E, ET);
    // pool + predict
    k_pool<<<(n * 64 + B - 1) / B, B, 0, stream>>>(out2, b2, batch, pooled, cnt, n);
    k_predict<<<(G * 64 + B - 1) / B, B, 0, stream>>>(pooled, cnt, Wp, bp, out, G);
}

// Round 2
// 746.729 us; speedup vs baseline: 2.0366x; 2.0366x over previous
//
#include <hip/hip_runtime.h>
#include <math.h>

#define NEG_SLOPE 0.2f

__device__ __forceinline__ float lrelu(float x) { return x > 0.f ? x : NEG_SLOPE * x; }

// ---- Layer 1: node transform, in=5 -> out=64 (xl and xr) ----
__global__ void k_transform1(const float* __restrict__ x,
                             const float* __restrict__ W1l, const float* __restrict__ W1r,
                             float* __restrict__ xl, float* __restrict__ xr, int n) {
    __shared__ float sWl[5 * 64], sWr[5 * 64];
    int t = threadIdx.x;
    for (int i = t; i < 5 * 64; i += blockDim.x) { sWl[i] = W1l[i]; sWr[i] = W1r[i]; }
    __syncthreads();
    int tid = blockIdx.x * blockDim.x + t;
    if (tid >= n * 64) return;
    int node = tid >> 6, j = tid & 63;
    const float* xp = x + node * 5;
    float x0 = xp[0], x1 = xp[1], x2 = xp[2], x3 = xp[3], x4 = xp[4];
    float al = x0 * sWl[j] + x1 * sWl[64 + j] + x2 * sWl[128 + j] + x3 * sWl[192 + j] + x4 * sWl[256 + j];
    float ar = x0 * sWr[j] + x1 * sWr[64 + j] + x2 * sWr[128 + j] + x3 * sWr[192 + j] + x4 * sWr[256 + j];
    xl[tid] = al; xr[tid] = ar;
}

// ---- CSR build: histogram of dst ----
__global__ void k_hist(const int* __restrict__ ei, int* __restrict__ counts, int E, int ET) {
    int e = blockIdx.x * blockDim.x + threadIdx.x;
    if (e >= ET) return;
    int dst = (e < E) ? ei[E + e] : (e - E);
    atomicAdd(&counts[dst], 1);
}

// ---- exclusive scan, 3-kernel (n=50000 -> 196 blocks of 256) ----
__global__ void k_scan1(const int* __restrict__ counts, int* __restrict__ starts,
                        int* __restrict__ bsum, int n) {
    __shared__ int sh[256];
    int t = threadIdx.x, i = blockIdx.x * 256 + t;
    int v = (i < n) ? counts[i] : 0;
    sh[t] = v; __syncthreads();
    for (int off = 1; off < 256; off <<= 1) {
        int u = (t >= off) ? sh[t - off] : 0;
        __syncthreads();
        sh[t] += u;
        __syncthreads();
    }
    if (i < n) starts[i] = sh[t] - v;          // exclusive
    if (t == 255) bsum[blockIdx.x] = sh[t];    // block total
}

__global__ void k_scan2(int* __restrict__ bsum, int nb) {
    __shared__ int sh[256];
    int t = threadIdx.x;
    int v = (t < nb) ? bsum[t] : 0;
    sh[t] = v; __syncthreads();
    for (int off = 1; off < 256; off <<= 1) {
        int u = (t >= off) ? sh[t - off] : 0;
        __syncthreads();
        sh[t] += u;
        __syncthreads();
    }
    if (t < nb) bsum[t] = sh[t] - v;           // exclusive
}

__global__ void k_scan3(int* __restrict__ starts, const int* __restrict__ bsum, int n, int ET) {
    int i = blockIdx.x * blockDim.x + threadIdx.x;
    if (i < n) starts[i] += bsum[i >> 8];
    else if (i == n) starts[n] = ET;
}

// ---- CSR build: scatter src ids into dst buckets ----
__global__ void k_scatter(const int* __restrict__ ei, const int* __restrict__ starts,
                          int* __restrict__ cursor, int* __restrict__ ssrc, int E, int ET) {
    int e = blockIdx.x * blockDim.x + threadIdx.x;
    if (e >= ET) return;
    int src, dst;
    if (e < E) { src = ei[e]; dst = ei[E + e]; } else { src = dst = e - E; }
    int pos = atomicAdd(&cursor[dst], 1);
    ssrc[starts[dst] + pos] = src;
}

// ---- Layer 1 fused: per-dst online softmax + aggregation. Wave per node. ----
// Lanes: h = lane>>4 (4 heads), d = lane&15 (16 dims). Logit reduce within 16-lane group.
__global__ void k_gat1(const int* __restrict__ ssrc, const int* __restrict__ starts,
                       const float* __restrict__ xl, const float* __restrict__ xr,
                       const float* __restrict__ att1, float* __restrict__ out1, int n) {
    int node = (blockIdx.x * blockDim.x + threadIdx.x) >> 6;
    if (node >= n) return;
    int lane = threadIdx.x & 63;
    float xr_d = xr[(size_t)node * 64 + lane];
    float attv = att1[lane];                   // att1 layout [4,16] == [lane]
    float m = -INFINITY, den = 0.f, acc = 0.f;
    int beg = starts[node], end = starts[node + 1];   // deg >= 1 (self-loop)
    float a_n = xl[(size_t)ssrc[beg] * 64 + lane];
    for (int k = beg; k < end; ++k) {
        float a = a_n;
        if (k + 1 < end) a_n = xl[(size_t)ssrc[k + 1] * 64 + lane];  // prefetch
        float s = lrelu(a + xr_d) * attv;
        s += __shfl_xor(s, 1, 64);
        s += __shfl_xor(s, 2, 64);
        s += __shfl_xor(s, 4, 64);
        s += __shfl_xor(s, 8, 64);             // e_h replicated in 16-lane group
        float mn = fmaxf(m, s);
        float scale = __expf(m - mn);          // first iter: exp(-inf)=0
        float p = __expf(s - mn);
        den = den * scale + p;
        acc = acc * scale + p * a;
        m = mn;
    }
    out1[(size_t)node * 64 + lane] = acc / (den + 1e-16f);
}

// ---- Layer 2: h1 = relu(out1 + b1); hl2 = h1@W2l; hr2 = h1@W2r ----
__global__ void k_transform2(const float* __restrict__ out1, const float* __restrict__ b1,
                             const float* __restrict__ W2l, const float* __restrict__ W2r,
                             float* __restrict__ hl, float* __restrict__ hr, int n) {
    __shared__ float sh[4][64];
    int t = threadIdx.x;
    int local = t >> 6, j = t & 63;
    int node = blockIdx.x * 4 + local;
    if (node < n) {
        float v = out1[(size_t)node * 64 + j] + b1[j];
        sh[local][j] = v > 0.f ? v : 0.f;
    }
    __syncthreads();
    if (node >= n) return;
    float accl = 0.f, accr = 0.f;
#pragma unroll 8
    for (int k = 0; k < 64; ++k) {
        float hv = sh[local][k];
        accl += hv * W2l[k * 64 + j];
        accr += hv * W2r[k * 64 + j];
    }
    hl[(size_t)node * 64 + j] = accl;
    hr[(size_t)node * 64 + j] = accr;
}

// ---- Layer 2 fused: wave per node, full-wave logit reduce, online softmax ----
__global__ void k_gat2(const int* __restrict__ ssrc, const int* __restrict__ starts,
                       const float* __restrict__ hl, const float* __restrict__ hr,
                       const float* __restrict__ att2, float* __restrict__ out2, int n) {
    int node = (blockIdx.x * blockDim.x + threadIdx.x) >> 6;
    if (node >= n) return;
    int lane = threadIdx.x & 63;
    float hr_d = hr[(size_t)node * 64 + lane];
    float attv = att2[lane];
    float m = -INFINITY, den = 0.f, acc = 0.f;
    int beg = starts[node], end = starts[node + 1];
    float a_n = hl[(size_t)ssrc[beg] * 64 + lane];
    for (int k = beg; k < end; ++k) {
        float a = a_n;
        if (k + 1 < end) a_n = hl[(size_t)ssrc[k + 1] * 64 + lane];
        float s = lrelu(a + hr_d) * attv;
        s += __shfl_xor(s, 1, 64);
        s += __shfl_xor(s, 2, 64);
        s += __shfl_xor(s, 4, 64);
        s += __shfl_xor(s, 8, 64);
        s += __shfl_xor(s, 16, 64);
        s += __shfl_xor(s, 32, 64);            // e replicated across wave
        float mn = fmaxf(m, s);
        float scale = __expf(m - mn);
        float p = __expf(s - mn);
        den = den * scale + p;
        acc = acc * scale + p * a;
        m = mn;
    }
    out2[(size_t)node * 64 + lane] = acc / (den + 1e-16f);
}

// ---- Pool: pooled[batch[node]] += relu(out2[node]+b2); cnt[g] += 1 ----
__global__ void k_pool(const float* __restrict__ out2, const float* __restrict__ b2,
                       const int* __restrict__ batch,
                       float* __restrict__ pooled, float* __restrict__ cnt, int n) {
    int tid = blockIdx.x * blockDim.x + threadIdx.x;
    if (tid >= n * 64) return;
    int node = tid >> 6, f = tid & 63;
    float v = out2[tid] + b2[f];
    v = v > 0.f ? v : 0.f;
    int g = batch[node];
    atomicAdd(&pooled[g * 64 + f], v);
    if (f == 0) atomicAdd(&cnt[g], 1.0f);
}

// ---- Predict: out[g] = dot(pooled[g]/max(cnt,1), Wp) + bp ----
__global__ void k_predict(const float* __restrict__ pooled, const float* __restrict__ cnt,
                          const float* __restrict__ Wp, const float* __restrict__ bp,
                          float* __restrict__ out, int G) {
    int tid = blockIdx.x * blockDim.x + threadIdx.x;
    int g = tid >> 6;
    if (g >= G) return;
    int lane = threadIdx.x & 63;
    float c = cnt[g];
    if (c < 1.f) c = 1.f;
    float v = (pooled[g * 64 + lane] / c) * Wp[lane];
#pragma unroll
    for (int off = 32; off > 0; off >>= 1) v += __shfl_down(v, off, 64);
    if (lane == 0) out[g] = v + bp[0];
}

extern "C" void kernel_launch(void* const* d_in, const int* in_sizes, int n_in,
                              void* d_out, int out_size, void* d_ws, size_t ws_size,
                              hipStream_t stream) {
    const float* x    = (const float*)d_in[0];
    const int*   ei   = (const int*)d_in[1];
    const int*   batch= (const int*)d_in[2];
    const float* W1l  = (const float*)d_in[3];
    const float* W1r  = (const float*)d_in[4];
    const float* att1 = (const float*)d_in[5];
    const float* b1   = (const float*)d_in[6];
    const float* W2l  = (const float*)d_in[7];
    const float* W2r  = (const float*)d_in[8];
    const float* att2 = (const float*)d_in[9];
    const float* b2   = (const float*)d_in[10];
    const float* Wp   = (const float*)d_in[11];
    const float* bp   = (const float*)d_in[12];
    float* out = (float*)d_out;

    const int n  = in_sizes[0] / 5;        // 50000
    const int E  = in_sizes[1] / 2;        // 1600000
    const int ET = E + n;                  // +self-loops
    const int G  = out_size;               // 512

    // ---- workspace layout ----
    char* ws = (char*)d_ws;
    size_t off = 0;
    auto alloc_f = [&](size_t cnt_) { float* p = (float*)(ws + off); off += cnt_ * 4; return p; };
    auto alloc_i = [&](size_t cnt_) { int*   p = (int*)(ws + off);  off += cnt_ * 4; return p; };
    float* buf_l  = alloc_f((size_t)n * 64);   // xl1 / hl2
    float* buf_r  = alloc_f((size_t)n * 64);   // xr1 / hr2
    float* out1   = alloc_f((size_t)n * 64);
    float* out2   = alloc_f((size_t)n * 64);
    float* pooled = alloc_f((size_t)G * 64);   // zero-init region start
    float* cnt    = alloc_f((size_t)G);
    int*   counts = alloc_i(n);                //   (continues zero region)
    int*   cursor = alloc_i(n);
    int*   starts = alloc_i(n + 1);
    int*   bsum   = alloc_i(256);
    int*   ssrc   = alloc_i(ET);

    // zero: pooled, cnt, counts, cursor (contiguous)
    size_t zero_bytes = ((size_t)G * 64 + G + n + n) * 4;
    hipMemsetAsync(pooled, 0, zero_bytes, stream);

    const int B = 256;
    const int nb = (n + 255) / 256;            // scan blocks (196)

    // node transform layer 1 (independent of CSR build)
    k_transform1<<<(n * 64 + B - 1) / B, B, 0, stream>>>(x, W1l, W1r, buf_l, buf_r, n);

    // CSR build (dst-sorted src list), reused by both layers
    k_hist<<<(ET + B - 1) / B, B, 0, stream>>>(ei, counts, E, ET);
    k_scan1<<<nb, 256, 0, stream>>>(counts, starts, bsum, n);
    k_scan2<<<1, 256, 0, stream>>>(bsum, nb);
    k_scan3<<<(n + 1 + B - 1) / B, B, 0, stream>>>(starts, bsum, n, ET);
    k_scatter<<<(ET + B - 1) / B, B, 0, stream>>>(ei, starts, cursor, ssrc, E, ET);

    // fused GAT layers
    k_gat1<<<((size_t)n * 64 + B - 1) / B, B, 0, stream>>>(ssrc, starts, buf_l, buf_r, att1, out1, n);
    k_transform2<<<(n + 3) / 4, B, 0, stream>>>(out1, b1, W2l, W2r, buf_l, buf_r, n);
    k_gat2<<<((size_t)n * 64 + B - 1) / B, B, 0, stream>>>(ssrc, starts, buf_l, buf_r, att2, out2, n);

    // pool + predict
    k_pool<<<(n * 64 + B - 1) / B, B, 0, stream>>>(out2, b2, batch, pooled, cnt, n);
    k_predict<<<(G * 64 + B - 1) / B, B, 0, stream>>>(pooled, cnt, Wp, bp, out, G);
}

// Round 3
// 597.180 us; speedup vs baseline: 2.5466x; 1.2504x over previous
//
#include <hip/hip_runtime.h>
#include <math.h>

#define NEG_SLOPE 0.2f

__device__ __forceinline__ float lrelu(float x) { return x > 0.f ? x : NEG_SLOPE * x; }

// ---- CSR build: histogram of dst ----
__global__ void k_hist(const int* __restrict__ ei, int* __restrict__ counts, int E, int ET) {
    int e = blockIdx.x * blockDim.x + threadIdx.x;
    if (e >= ET) return;
    int dst = (e < E) ? ei[E + e] : (e - E);
    atomicAdd(&counts[dst], 1);
}

// ---- exclusive scan, 3-kernel (n=50000 -> 196 blocks of 256) ----
__global__ void k_scan1(const int* __restrict__ counts, int* __restrict__ starts,
                        int* __restrict__ bsum, int n) {
    __shared__ int sh[256];
    int t = threadIdx.x, i = blockIdx.x * 256 + t;
    int v = (i < n) ? counts[i] : 0;
    sh[t] = v; __syncthreads();
    for (int off = 1; off < 256; off <<= 1) {
        int u = (t >= off) ? sh[t - off] : 0;
        __syncthreads();
        sh[t] += u;
        __syncthreads();
    }
    if (i < n) starts[i] = sh[t] - v;          // exclusive
    if (t == 255) bsum[blockIdx.x] = sh[t];    // block total
}

__global__ void k_scan2(int* __restrict__ bsum, int nb) {
    __shared__ int sh[256];
    int t = threadIdx.x;
    int v = (t < nb) ? bsum[t] : 0;
    sh[t] = v; __syncthreads();
    for (int off = 1; off < 256; off <<= 1) {
        int u = (t >= off) ? sh[t - off] : 0;
        __syncthreads();
        sh[t] += u;
        __syncthreads();
    }
    if (t < nb) bsum[t] = sh[t] - v;           // exclusive
}

__global__ void k_scan3(int* __restrict__ starts, const int* __restrict__ bsum, int n, int ET) {
    int i = blockIdx.x * blockDim.x + threadIdx.x;
    if (i < n) starts[i] += bsum[i >> 8];
    else if (i == n) starts[n] = ET;
}

// ---- CSR build: scatter src ids into dst buckets ----
__global__ void k_scatter(const int* __restrict__ ei, const int* __restrict__ starts,
                          int* __restrict__ cursor, int* __restrict__ ssrc, int E, int ET) {
    int e = blockIdx.x * blockDim.x + threadIdx.x;
    if (e >= ET) return;
    int src, dst;
    if (e < E) { src = ei[e]; dst = ei[E + e]; } else { src = dst = e - E; }
    int pos = atomicAdd(&cursor[dst], 1);
    ssrc[starts[dst] + pos] = src;
}

// ---- Layer 1 fused: wave per node. xl/xr recomputed on the fly from x (rank 5).
// x is 1 MB -> L2-resident; src row loads are wave-uniform scalar (broadcast).
// Lanes: h = lane>>4 (4 heads), d = lane&15. Logit reduce within 16-lane group.
__global__ void k_gat1(const int* __restrict__ ssrc, const int* __restrict__ starts,
                       const float* __restrict__ x,
                       const float* __restrict__ W1l, const float* __restrict__ W1r,
                       const float* __restrict__ att1, float* __restrict__ out1, int n) {
    int node = (blockIdx.x * blockDim.x + threadIdx.x) >> 6;
    if (node >= n) return;
    int lane = threadIdx.x & 63;
    float wl[5], wr[5];
#pragma unroll
    for (int k = 0; k < 5; ++k) { wl[k] = W1l[k * 64 + lane]; wr[k] = W1r[k * 64 + lane]; }
    float attv = att1[lane];                   // att1 layout [4,16] == [lane]
    const float* xn = x + (size_t)node * 5;
    float xr_d = xn[0] * wr[0] + xn[1] * wr[1] + xn[2] * wr[2] + xn[3] * wr[3] + xn[4] * wr[4];
    float m = -INFINITY, den = 0.f, acc = 0.f;
    int beg = starts[node], end = starts[node + 1];   // deg >= 1 (self-loop)
    int k = beg;
    for (; k + 3 < end; k += 4) {
        float a[4], s[4];
#pragma unroll
        for (int j = 0; j < 4; ++j) {
            int sj = __builtin_amdgcn_readfirstlane(ssrc[k + j]);
            const float* xs = x + (size_t)sj * 5;
            float x0 = xs[0], x1 = xs[1], x2 = xs[2], x3 = xs[3], x4 = xs[4];
            a[j] = x0 * wl[0] + x1 * wl[1] + x2 * wl[2] + x3 * wl[3] + x4 * wl[4];
            s[j] = lrelu(a[j] + xr_d) * attv;
        }
#pragma unroll
        for (int j = 0; j < 4; ++j) {          // 4 independent shuffle chains (ILP)
            s[j] += __shfl_xor(s[j], 1, 64);
            s[j] += __shfl_xor(s[j], 2, 64);
            s[j] += __shfl_xor(s[j], 4, 64);
            s[j] += __shfl_xor(s[j], 8, 64);
        }
        float mb = fmaxf(fmaxf(s[0], s[1]), fmaxf(s[2], s[3]));
        float mn = fmaxf(m, mb);
        float scale = __expf(m - mn);          // first batch: exp(-inf)=0
        den *= scale; acc *= scale;
#pragma unroll
        for (int j = 0; j < 4; ++j) {
            float p = __expf(s[j] - mn);
            den += p; acc += p * a[j];
        }
        m = mn;
    }
    for (; k < end; ++k) {
        int sj = __builtin_amdgcn_readfirstlane(ssrc[k]);
        const float* xs = x + (size_t)sj * 5;
        float a = xs[0] * wl[0] + xs[1] * wl[1] + xs[2] * wl[2] + xs[3] * wl[3] + xs[4] * wl[4];
        float s = lrelu(a + xr_d) * attv;
        s += __shfl_xor(s, 1, 64);
        s += __shfl_xor(s, 2, 64);
        s += __shfl_xor(s, 4, 64);
        s += __shfl_xor(s, 8, 64);
        float mn = fmaxf(m, s);
        float scale = __expf(m - mn);
        float p = __expf(s - mn);
        den = den * scale + p;
        acc = acc * scale + p * a;
        m = mn;
    }
    out1[(size_t)node * 64 + lane] = acc / (den + 1e-16f);
}

// ---- Layer 2: h1 = relu(out1 + b1); hl2 = h1@W2l; hr2 = h1@W2r ----
__global__ void k_transform2(const float* __restrict__ out1, const float* __restrict__ b1,
                             const float* __restrict__ W2l, const float* __restrict__ W2r,
                             float* __restrict__ hl, float* __restrict__ hr, int n) {
    __shared__ float sh[4][64];
    int t = threadIdx.x;
    int local = t >> 6, j = t & 63;
    int node = blockIdx.x * 4 + local;
    if (node < n) {
        float v = out1[(size_t)node * 64 + j] + b1[j];
        sh[local][j] = v > 0.f ? v : 0.f;
    }
    __syncthreads();
    if (node >= n) return;
    float accl = 0.f, accr = 0.f;
#pragma unroll 8
    for (int k = 0; k < 64; ++k) {
        float hv = sh[local][k];
        accl += hv * W2l[k * 64 + j];
        accr += hv * W2r[k * 64 + j];
    }
    hl[(size_t)node * 64 + j] = accl;
    hr[(size_t)node * 64 + j] = accr;
}

// ---- Layer 2 fused: wave per node, batched-by-4 edges for ILP/MLP ----
__global__ void k_gat2(const int* __restrict__ ssrc, const int* __restrict__ starts,
                       const float* __restrict__ hl, const float* __restrict__ hr,
                       const float* __restrict__ att2, float* __restrict__ out2, int n) {
    int node = (blockIdx.x * blockDim.x + threadIdx.x) >> 6;
    if (node >= n) return;
    int lane = threadIdx.x & 63;
    float hr_d = hr[(size_t)node * 64 + lane];
    float attv = att2[lane];
    float m = -INFINITY, den = 0.f, acc = 0.f;
    int beg = starts[node], end = starts[node + 1];
    int k = beg;
    for (; k + 3 < end; k += 4) {
        float a[4], s[4];
#pragma unroll
        for (int j = 0; j < 4; ++j) {          // 4 concurrent gathers (MLP)
            int sj = __builtin_amdgcn_readfirstlane(ssrc[k + j]);
            a[j] = hl[(size_t)sj * 64 + lane];
        }
#pragma unroll
        for (int j = 0; j < 4; ++j) s[j] = lrelu(a[j] + hr_d) * attv;
#pragma unroll
        for (int j = 0; j < 4; ++j) {          // 4 independent 6-step chains
            s[j] += __shfl_xor(s[j], 1, 64);
            s[j] += __shfl_xor(s[j], 2, 64);
            s[j] += __shfl_xor(s[j], 4, 64);
            s[j] += __shfl_xor(s[j], 8, 64);
            s[j] += __shfl_xor(s[j], 16, 64);
            s[j] += __shfl_xor(s[j], 32, 64);
        }
        float mb = fmaxf(fmaxf(s[0], s[1]), fmaxf(s[2], s[3]));
        float mn = fmaxf(m, mb);
        float scale = __expf(m - mn);
        den *= scale; acc *= scale;
#pragma unroll
        for (int j = 0; j < 4; ++j) {
            float p = __expf(s[j] - mn);
            den += p; acc += p * a[j];
        }
        m = mn;
    }
    for (; k < end; ++k) {
        int sj = __builtin_amdgcn_readfirstlane(ssrc[k]);
        float a = hl[(size_t)sj * 64 + lane];
        float s = lrelu(a + hr_d) * attv;
        s += __shfl_xor(s, 1, 64);
        s += __shfl_xor(s, 2, 64);
        s += __shfl_xor(s, 4, 64);
        s += __shfl_xor(s, 8, 64);
        s += __shfl_xor(s, 16, 64);
        s += __shfl_xor(s, 32, 64);
        float mn = fmaxf(m, s);
        float scale = __expf(m - mn);
        float p = __expf(s - mn);
        den = den * scale + p;
        acc = acc * scale + p * a;
        m = mn;
    }
    out2[(size_t)node * 64 + lane] = acc / (den + 1e-16f);
}

// ---- Pool: pooled[batch[node]] += relu(out2[node]+b2); cnt[g] += 1 ----
__global__ void k_pool(const float* __restrict__ out2, const float* __restrict__ b2,
                       const int* __restrict__ batch,
                       float* __restrict__ pooled, float* __restrict__ cnt, int n) {
    int tid = blockIdx.x * blockDim.x + threadIdx.x;
    if (tid >= n * 64) return;
    int node = tid >> 6, f = tid & 63;
    float v = out2[tid] + b2[f];
    v = v > 0.f ? v : 0.f;
    int g = batch[node];
    atomicAdd(&pooled[g * 64 + f], v);
    if (f == 0) atomicAdd(&cnt[g], 1.0f);
}

// ---- Predict: out[g] = dot(pooled[g]/max(cnt,1), Wp) + bp ----
__global__ void k_predict(const float* __restrict__ pooled, const float* __restrict__ cnt,
                          const float* __restrict__ Wp, const float* __restrict__ bp,
                          float* __restrict__ out, int G) {
    int tid = blockIdx.x * blockDim.x + threadIdx.x;
    int g = tid >> 6;
    if (g >= G) return;
    int lane = threadIdx.x & 63;
    float c = cnt[g];
    if (c < 1.f) c = 1.f;
    float v = (pooled[g * 64 + lane] / c) * Wp[lane];
#pragma unroll
    for (int off = 32; off > 0; off >>= 1) v += __shfl_down(v, off, 64);
    if (lane == 0) out[g] = v + bp[0];
}

extern "C" void kernel_launch(void* const* d_in, const int* in_sizes, int n_in,
                              void* d_out, int out_size, void* d_ws, size_t ws_size,
                              hipStream_t stream) {
    const float* x    = (const float*)d_in[0];
    const int*   ei   = (const int*)d_in[1];
    const int*   batch= (const int*)d_in[2];
    const float* W1l  = (const float*)d_in[3];
    const float* W1r  = (const float*)d_in[4];
    const float* att1 = (const float*)d_in[5];
    const float* b1   = (const float*)d_in[6];
    const float* W2l  = (const float*)d_in[7];
    const float* W2r  = (const float*)d_in[8];
    const float* att2 = (const float*)d_in[9];
    const float* b2   = (const float*)d_in[10];
    const float* Wp   = (const float*)d_in[11];
    const float* bp   = (const float*)d_in[12];
    float* out = (float*)d_out;

    const int n  = in_sizes[0] / 5;        // 50000
    const int E  = in_sizes[1] / 2;        // 1600000
    const int ET = E + n;                  // +self-loops
    const int G  = out_size;               // 512

    // ---- workspace layout ----
    char* ws = (char*)d_ws;
    size_t off = 0;
    auto alloc_f = [&](size_t cnt_) { float* p = (float*)(ws + off); off += cnt_ * 4; return p; };
    auto alloc_i = [&](size_t cnt_) { int*   p = (int*)(ws + off);  off += cnt_ * 4; return p; };
    float* buf_l  = alloc_f((size_t)n * 64);   // hl2
    float* buf_r  = alloc_f((size_t)n * 64);   // hr2
    float* out1   = alloc_f((size_t)n * 64);
    float* out2   = alloc_f((size_t)n * 64);
    float* pooled = alloc_f((size_t)G * 64);   // zero-init region start
    float* cnt    = alloc_f((size_t)G);
    int*   counts = alloc_i(n);                //   (continues zero region)
    int*   cursor = alloc_i(n);
    int*   starts = alloc_i(n + 1);
    int*   bsum   = alloc_i(256);
    int*   ssrc   = alloc_i(ET);

    // zero: pooled, cnt, counts, cursor (contiguous)
    size_t zero_bytes = ((size_t)G * 64 + G + n + n) * 4;
    hipMemsetAsync(pooled, 0, zero_bytes, stream);

    const int B = 256;
    const int nb = (n + 255) / 256;            // scan blocks (196)

    // CSR build (dst-sorted src list), reused by both layers
    k_hist<<<(ET + B - 1) / B, B, 0, stream>>>(ei, counts, E, ET);
    k_scan1<<<nb, 256, 0, stream>>>(counts, starts, bsum, n);
    k_scan2<<<1, 256, 0, stream>>>(bsum, nb);
    k_scan3<<<(n + 1 + B - 1) / B, B, 0, stream>>>(starts, bsum, n, ET);
    k_scatter<<<(ET + B - 1) / B, B, 0, stream>>>(ei, starts, cursor, ssrc, E, ET);

    // fused GAT layers
    k_gat1<<<((size_t)n * 64 + B - 1) / B, B, 0, stream>>>(ssrc, starts, x, W1l, W1r, att1, out1, n);
    k_transform2<<<(n + 3) / 4, B, 0, stream>>>(out1, b1, W2l, W2r, buf_l, buf_r, n);
    k_gat2<<<((size_t)n * 64 + B - 1) / B, B, 0, stream>>>(ssrc, starts, buf_l, buf_r, att2, out2, n);

    // pool + predict
    k_pool<<<(n * 64 + B - 1) / B, B, 0, stream>>>(out2, b2, batch, pooled, cnt, n);
    k_predict<<<(G * 64 + B - 1) / B, B, 0, stream>>>(pooled, cnt, Wp, bp, out, G);
}

// Round 4
// 518.517 us; speedup vs baseline: 2.9330x; 1.1517x over previous
//
#include <hip/hip_runtime.h>
#include <hip/hip_fp16.h>
#include <math.h>

#define NEG_SLOPE 0.2f

__device__ __forceinline__ float lrelu(float x) { return x > 0.f ? x : NEG_SLOPE * x; }

// ---- CSR build: histogram of dst ----
__global__ void k_hist(const int* __restrict__ ei, int* __restrict__ counts, int E, int ET) {
    int e = blockIdx.x * blockDim.x + threadIdx.x;
    if (e >= ET) return;
    int dst = (e < E) ? ei[E + e] : (e - E);
    atomicAdd(&counts[dst], 1);
}

// ---- exclusive scan, 3-kernel (n=50000 -> 196 blocks of 256) ----
__global__ void k_scan1(const int* __restrict__ counts, int* __restrict__ starts,
                        int* __restrict__ bsum, int n) {
    __shared__ int sh[256];
    int t = threadIdx.x, i = blockIdx.x * 256 + t;
    int v = (i < n) ? counts[i] : 0;
    sh[t] = v; __syncthreads();
    for (int off = 1; off < 256; off <<= 1) {
        int u = (t >= off) ? sh[t - off] : 0;
        __syncthreads();
        sh[t] += u;
        __syncthreads();
    }
    if (i < n) starts[i] = sh[t] - v;          // exclusive
    if (t == 255) bsum[blockIdx.x] = sh[t];    // block total
}

__global__ void k_scan2(int* __restrict__ bsum, int nb) {
    __shared__ int sh[256];
    int t = threadIdx.x;
    int v = (t < nb) ? bsum[t] : 0;
    sh[t] = v; __syncthreads();
    for (int off = 1; off < 256; off <<= 1) {
        int u = (t >= off) ? sh[t - off] : 0;
        __syncthreads();
        sh[t] += u;
        __syncthreads();
    }
    if (t < nb) bsum[t] = sh[t] - v;           // exclusive
}

__global__ void k_scan3(int* __restrict__ starts, const int* __restrict__ bsum, int n, int ET) {
    int i = blockIdx.x * blockDim.x + threadIdx.x;
    if (i < n) starts[i] += bsum[i >> 8];
    else if (i == n) starts[n] = ET;
}

// ---- CSR build: scatter src ids into dst buckets ----
__global__ void k_scatter(const int* __restrict__ ei, const int* __restrict__ starts,
                          int* __restrict__ cursor, int* __restrict__ ssrc, int E, int ET) {
    int e = blockIdx.x * blockDim.x + threadIdx.x;
    if (e >= ET) return;
    int src, dst;
    if (e < E) { src = ei[e]; dst = ei[E + e]; } else { src = dst = e - E; }
    int pos = atomicAdd(&cursor[dst], 1);
    ssrc[starts[dst] + pos] = src;
}

// ---- Layer 1 fused: GATv2 (wave per node, on-the-fly rank-5 transform)
//      + layer-2 node transform epilogue (h1 in LDS, 64-FMA vs W2l/W2r).
//      Writes hl as fp16 (gathered by k_gat2), hr as fp32 (coalesced read).
__global__ void k_gat1(const int* __restrict__ ssrc, const int* __restrict__ starts,
                       const float* __restrict__ x,
                       const float* __restrict__ W1l, const float* __restrict__ W1r,
                       const float* __restrict__ att1, const float* __restrict__ b1,
                       const float* __restrict__ W2l, const float* __restrict__ W2r,
                       __half* __restrict__ hl, float* __restrict__ hr, int n) {
    __shared__ float sh[4][64];
    int t = threadIdx.x;
    int local = t >> 6, lane = t & 63;
    int node = blockIdx.x * 4 + local;
    float h1 = 0.f;
    if (node < n) {
        float wl[5], wr[5];
#pragma unroll
        for (int q = 0; q < 5; ++q) { wl[q] = W1l[q * 64 + lane]; wr[q] = W1r[q * 64 + lane]; }
        float attv = att1[lane];               // att1 layout [4,16] == [lane]
        const float* xn = x + (size_t)node * 5;
        float xr_d = xn[0] * wr[0] + xn[1] * wr[1] + xn[2] * wr[2] + xn[3] * wr[3] + xn[4] * wr[4];
        float m = -INFINITY, den = 0.f, acc = 0.f;
        int beg = starts[node], end = starts[node + 1];   // deg >= 1 (self-loop)
        int k = beg;
        for (; k + 7 < end; k += 8) {
            float a[8], s[8];
#pragma unroll
            for (int j = 0; j < 8; ++j) {
                int sj = __builtin_amdgcn_readfirstlane(ssrc[k + j]);
                const float* xs = x + (size_t)sj * 5;
                float x0 = xs[0], x1 = xs[1], x2 = xs[2], x3 = xs[3], x4 = xs[4];
                a[j] = x0 * wl[0] + x1 * wl[1] + x2 * wl[2] + x3 * wl[3] + x4 * wl[4];
                s[j] = lrelu(a[j] + xr_d) * attv;
            }
#pragma unroll
            for (int j = 0; j < 8; ++j) {      // 8 independent 16-lane reduce chains
                s[j] += __shfl_xor(s[j], 1, 64);
                s[j] += __shfl_xor(s[j], 2, 64);
                s[j] += __shfl_xor(s[j], 4, 64);
                s[j] += __shfl_xor(s[j], 8, 64);
            }
            float mb = fmaxf(fmaxf(fmaxf(s[0], s[1]), fmaxf(s[2], s[3])),
                             fmaxf(fmaxf(s[4], s[5]), fmaxf(s[6], s[7])));
            float mn = fmaxf(m, mb);
            float scale = __expf(m - mn);      // first batch: exp(-inf)=0
            den *= scale; acc *= scale;
#pragma unroll
            for (int j = 0; j < 8; ++j) {
                float p = __expf(s[j] - mn);
                den += p; acc += p * a[j];
            }
            m = mn;
        }
        for (; k < end; ++k) {
            int sj = __builtin_amdgcn_readfirstlane(ssrc[k]);
            const float* xs = x + (size_t)sj * 5;
            float a = xs[0] * wl[0] + xs[1] * wl[1] + xs[2] * wl[2] + xs[3] * wl[3] + xs[4] * wl[4];
            float s = lrelu(a + xr_d) * attv;
            s += __shfl_xor(s, 1, 64);
            s += __shfl_xor(s, 2, 64);
            s += __shfl_xor(s, 4, 64);
            s += __shfl_xor(s, 8, 64);
            float mn = fmaxf(m, s);
            float scale = __expf(m - mn);
            float p = __expf(s - mn);
            den = den * scale + p;
            acc = acc * scale + p * a;
            m = mn;
        }
        float o = acc / (den + 1e-16f) + b1[lane];
        h1 = o > 0.f ? o : 0.f;                // relu (dropout=identity at eval)
    }
    sh[local][lane] = h1;
    __syncthreads();
    if (node >= n) return;
    // ---- layer-2 transform: hl = h1@W2l, hr = h1@W2r ----
    float accl = 0.f, accr = 0.f;
#pragma unroll 8
    for (int q = 0; q < 64; ++q) {
        float hv = sh[local][q];
        accl += hv * W2l[q * 64 + lane];
        accr += hv * W2r[q * 64 + lane];
    }
    hl[(size_t)node * 64 + lane] = __float2half(accl);
    hr[(size_t)node * 64 + lane] = accr;
}

// ---- Layer 2 fused: wave per node, fp16 gathers batched by 8, online softmax,
//      + pool epilogue (relu + atomicAdd into pooled[batch[node]]).
__global__ void k_gat2(const int* __restrict__ ssrc, const int* __restrict__ starts,
                       const __half* __restrict__ hl, const float* __restrict__ hr,
                       const float* __restrict__ att2, const float* __restrict__ b2,
                       const int* __restrict__ batch,
                       float* __restrict__ pooled, float* __restrict__ cnt, int n) {
    int node = (blockIdx.x * blockDim.x + threadIdx.x) >> 6;
    if (node >= n) return;
    int lane = threadIdx.x & 63;
    float hr_d = hr[(size_t)node * 64 + lane];
    float attv = att2[lane];
    float m = -INFINITY, den = 0.f, acc = 0.f;
    int beg = starts[node], end = starts[node + 1];
    int k = beg;
    for (; k + 7 < end; k += 8) {
        float a[8], s[8];
#pragma unroll
        for (int j = 0; j < 8; ++j) {          // 8 concurrent 128-B gathers (MLP)
            int sj = __builtin_amdgcn_readfirstlane(ssrc[k + j]);
            a[j] = __half2float(hl[(size_t)sj * 64 + lane]);
        }
#pragma unroll
        for (int j = 0; j < 8; ++j) s[j] = lrelu(a[j] + hr_d) * attv;
#pragma unroll
        for (int j = 0; j < 8; ++j) {          // 8 independent 6-step chains
            s[j] += __shfl_xor(s[j], 1, 64);
            s[j] += __shfl_xor(s[j], 2, 64);
            s[j] += __shfl_xor(s[j], 4, 64);
            s[j] += __shfl_xor(s[j], 8, 64);
            s[j] += __shfl_xor(s[j], 16, 64);
            s[j] += __shfl_xor(s[j], 32, 64);
        }
        float mb = fmaxf(fmaxf(fmaxf(s[0], s[1]), fmaxf(s[2], s[3])),
                         fmaxf(fmaxf(s[4], s[5]), fmaxf(s[6], s[7])));
        float mn = fmaxf(m, mb);
        float scale = __expf(m - mn);
        den *= scale; acc *= scale;
#pragma unroll
        for (int j = 0; j < 8; ++j) {
            float p = __expf(s[j] - mn);
            den += p; acc += p * a[j];
        }
        m = mn;
    }
    for (; k < end; ++k) {
        int sj = __builtin_amdgcn_readfirstlane(ssrc[k]);
        float a = __half2float(hl[(size_t)sj * 64 + lane]);
        float s = lrelu(a + hr_d) * attv;
        s += __shfl_xor(s, 1, 64);
        s += __shfl_xor(s, 2, 64);
        s += __shfl_xor(s, 4, 64);
        s += __shfl_xor(s, 8, 64);
        s += __shfl_xor(s, 16, 64);
        s += __shfl_xor(s, 32, 64);
        float mn = fmaxf(m, s);
        float scale = __expf(m - mn);
        float p = __expf(s - mn);
        den = den * scale + p;
        acc = acc * scale + p * a;
        m = mn;
    }
    // ---- pool epilogue ----
    float o = acc / (den + 1e-16f) + b2[lane];
    o = o > 0.f ? o : 0.f;                     // relu
    int g = batch[node];
    atomicAdd(&pooled[(size_t)g * 64 + lane], o);
    if (lane == 0) atomicAdd(&cnt[g], 1.0f);
}

// ---- Predict: out[g] = dot(pooled[g]/max(cnt,1), Wp) + bp ----
__global__ void k_predict(const float* __restrict__ pooled, const float* __restrict__ cnt,
                          const float* __restrict__ Wp, const float* __restrict__ bp,
                          float* __restrict__ out, int G) {
    int tid = blockIdx.x * blockDim.x + threadIdx.x;
    int g = tid >> 6;
    if (g >= G) return;
    int lane = threadIdx.x & 63;
    float c = cnt[g];
    if (c < 1.f) c = 1.f;
    float v = (pooled[(size_t)g * 64 + lane] / c) * Wp[lane];
#pragma unroll
    for (int off = 32; off > 0; off >>= 1) v += __shfl_down(v, off, 64);
    if (lane == 0) out[g] = v + bp[0];
}

extern "C" void kernel_launch(void* const* d_in, const int* in_sizes, int n_in,
                              void* d_out, int out_size, void* d_ws, size_t ws_size,
                              hipStream_t stream) {
    const float* x    = (const float*)d_in[0];
    const int*   ei   = (const int*)d_in[1];
    const int*   batch= (const int*)d_in[2];
    const float* W1l  = (const float*)d_in[3];
    const float* W1r  = (const float*)d_in[4];
    const float* att1 = (const float*)d_in[5];
    const float* b1   = (const float*)d_in[6];
    const float* W2l  = (const float*)d_in[7];
    const float* W2r  = (const float*)d_in[8];
    const float* att2 = (const float*)d_in[9];
    const float* b2   = (const float*)d_in[10];
    const float* Wp   = (const float*)d_in[11];
    const float* bp   = (const float*)d_in[12];
    float* out = (float*)d_out;

    const int n  = in_sizes[0] / 5;        // 50000
    const int E  = in_sizes[1] / 2;        // 1600000
    const int ET = E + n;                  // +self-loops
    const int G  = out_size;               // 512

    // ---- workspace layout ----
    char* ws = (char*)d_ws;
    size_t off = 0;
    auto alloc_b = [&](size_t bytes) { void* p = (void*)(ws + off); off += (bytes + 15) & ~15ull; return p; };
    __half* hl    = (__half*)alloc_b((size_t)n * 64 * 2);  // fp16 gather array (6.4 MB)
    float*  hr    = (float*)alloc_b((size_t)n * 64 * 4);
    float*  pooled= (float*)alloc_b((size_t)G * 64 * 4);   // zero region start
    float*  cnt   = (float*)alloc_b((size_t)G * 4);
    int*    counts= (int*)alloc_b((size_t)n * 4);
    int*    cursor= (int*)alloc_b((size_t)n * 4);          // zero region end
    int*    starts= (int*)alloc_b((size_t)(n + 1) * 4);
    int*    bsum  = (int*)alloc_b(256 * 4);
    int*    ssrc  = (int*)alloc_b((size_t)ET * 4);

    // zero: pooled..cursor (contiguous, 16B-aligned chunks)
    size_t zero_bytes = (size_t)((char*)cursor - (char*)pooled) + (size_t)n * 4;
    hipMemsetAsync(pooled, 0, zero_bytes, stream);

    const int B = 256;
    const int nb = (n + 255) / 256;            // scan blocks (196)

    // CSR build (dst-sorted src list), reused by both layers
    k_hist<<<(ET + B - 1) / B, B, 0, stream>>>(ei, counts, E, ET);
    k_scan1<<<nb, 256, 0, stream>>>(counts, starts, bsum, n);
    k_scan2<<<1, 256, 0, stream>>>(bsum, nb);
    k_scan3<<<(n + 1 + B - 1) / B, B, 0, stream>>>(starts, bsum, n, ET);
    k_scatter<<<(ET + B - 1) / B, B, 0, stream>>>(ei, starts, cursor, ssrc, E, ET);

    // fused GAT layer 1 + transform2  ->  hl (fp16), hr (fp32)
    k_gat1<<<(n + 3) / 4, B, 0, stream>>>(ssrc, starts, x, W1l, W1r, att1, b1, W2l, W2r, hl, hr, n);
    // fused GAT layer 2 + pool
    k_gat2<<<((size_t)n * 64 + B - 1) / B, B, 0, stream>>>(ssrc, starts, hl, hr, att2, b2, batch, pooled, cnt, n);
    // predict
    k_predict<<<(G * 64 + B - 1) / B, B, 0, stream>>>(pooled, cnt, Wp, bp, out, G);
}